// Round 2
// baseline (266.324 us; speedup 1.0000x reference)
//
#include <hip/hip_runtime.h>
#include <hip/hip_cooperative_groups.h>

namespace cg = cooperative_groups;

// NMS-r BP decoder, fully fused cooperative kernel.
// B=64, N=1024, M=512, DC=6, ITERS=5.
// cv [B,M,DC] lives in registers of its owning thread across iterations.
// Column sums via atomicAdd into 3 rotating S buffers (read/acc/zero).

constexpr int BB   = 64;
constexpr int NCOL = 1024;
constexpr int MROW = 512;
constexpr int KDC  = 6;
constexpr int ITERS = 5;
constexpr int TOT  = BB * NCOL;    // 65536 marg items
constexpr int NCHK = BB * MROW;    // 32768 check items
constexpr int THR  = 256;
constexpr int BLKS = TOT / THR;    // 256 blocks (1 per CU)
constexpr int CPB  = NCHK / BLKS;  // 128 check items per block

__device__ __forceinline__ float softplusf(float x) {
    // jax.nn.softplus = max(x,0) + log1p(exp(-|x|))
    return fmaxf(x, 0.f) + log1pf(expf(-fabsf(x)));
}
__device__ __forceinline__ float sgnf(float x) {
    return (x > 0.f) ? 1.f : ((x < 0.f) ? -1.f : 0.f);
}

__global__ void __launch_bounds__(THR, 1) k_fused(
        const float* __restrict__ soft,
        const int*   __restrict__ row_cols,
        const float* __restrict__ W1,    // [DC-1,4]
        const float* __restrict__ W2,    // [4]
        const float* __restrict__ bw1,
        const float* __restrict__ bw2,
        float* __restrict__ out,         // [ITERS+1, B, N]
        float* __restrict__ S0,
        float* __restrict__ S1,
        float* __restrict__ S2) {
    cg::grid_group grid = cg::this_grid();
    const int tid  = threadIdx.x;
    const int i    = blockIdx.x * THR + tid;       // marg item, [0, 65536)
    const bool ischk = tid < CPB;
    const int c    = blockIdx.x * CPB + tid;       // check item (valid if ischk)
    const int b    = c >> 9;                        // / MROW
    const int m    = c & (MROW - 1);

    const float sp1 = softplusf(bw1[0]);
    const float sp2 = softplusf(bw2[0]);

    // collapsed NN: w = W1 @ W2  (5-vector)
    float w[KDC - 1];
#pragma unroll
    for (int j = 0; j < KDC - 1; ++j) {
        float a = 0.f;
#pragma unroll
        for (int q = 0; q < 4; ++q) a += W1[j * 4 + q] * W2[q];
        w[j] = a;
    }

    const float soft_i = soft[i];
    out[i] = soft_i;     // soft_output_list[0] = soft_input
    S1[i] = 0.f;         // phase 0 accumulates into S1

    int   cols[KDC];
    float sft[KDC];      // sp1 * soft at my check's columns (iteration-invariant)
    float cv[KDC];       // my check row's cv, register-resident across iterations
    if (ischk) {
        const float* sb = soft + b * NCOL;
#pragma unroll
        for (int k = 0; k < KDC; ++k) {
            cols[k] = row_cols[m * KDC + k];
            sft[k]  = sp1 * sb[cols[k]];
            cv[k]   = 0.f;
        }
    }
    grid.sync();

    float* const Sb[3] = {S0, S1, S2};
#pragma unroll
    for (int p = 0; p < ITERS; ++p) {
        float* Sread = Sb[p % 3];         // colsum of iter p (p>=1)
        float* Sacc  = Sb[(p + 1) % 3];   // zeroed; this phase's atomics
        float* Szero = Sb[(p + 2) % 3];   // idle this phase -> zero for next

        if (p >= 1) out[(size_t)p * TOT + i] = sp2 * soft_i + Sread[i];
        Szero[i] = 0.f;

        if (ischk) {
            const float* Srb = Sread + b * NCOL;
            float sg[KDC], mag[KDC], P = 1.f;
#pragma unroll
            for (int k = 0; k < KDC; ++k) {
                // temp = colsum + sp1*soft (same association as reference)
                float v = (p == 0) ? sft[k] : (Srb[cols[k]] + sft[k]);
                v -= cv[k];
                float s = sgnf(v);
                sg[k] = s;
                P *= s;
                mag[k] = fabsf(v);
            }
            // stable ranks (permutation even under ties; tie order value-safe)
            int rank[KDC];
#pragma unroll
            for (int k = 0; k < KDC; ++k) {
                int r = 0;
#pragma unroll
                for (int j = 0; j < KDC; ++j)
                    r += (mag[j] < mag[k]) || (mag[j] == mag[k] && j < k);
                rank[k] = r;
            }
            // sorted array via static predicated selects (no runtime indexing
            // of register arrays -> no scratch, rule #20)
            float srt[KDC];
#pragma unroll
            for (int r = 0; r < KDC; ++r) {
                float v = 0.f;
#pragma unroll
                for (int k = 0; k < KDC; ++k) v = (rank[k] == r) ? mag[k] : v;
                srt[r] = v;
            }
            // leave-one-out dot via prefix/suffix of sorted-6:
            // removing rank r: val = pre[r] + suf[r]
            float pre[KDC];
            pre[0] = 0.f;
#pragma unroll
            for (int r = 0; r < KDC - 1; ++r) pre[r + 1] = pre[r] + srt[r] * w[r];
            float suf[KDC];
            suf[KDC - 1] = 0.f;
#pragma unroll
            for (int r = KDC - 2; r >= 0; --r) suf[r] = suf[r + 1] + srt[r + 1] * w[r];
            float valr[KDC];
#pragma unroll
            for (int r = 0; r < KDC; ++r) valr[r] = pre[r] + suf[r];

#pragma unroll
            for (int k = 0; k < KDC; ++k) {
                float val = 0.f;
#pragma unroll
                for (int r = 0; r < KDC; ++r) val = (rank[k] == r) ? valr[r] : val;
                float cvn = P * sg[k] * val;
                cv[k] = cvn;
                atomicAdd(&Sacc[b * NCOL + cols[k]], cvn);  // device-scope f32 atomic
            }
        }
        grid.sync();
    }
    // final marginalize: phase ITERS-1 accumulated into Sb[ITERS%3]
    out[(size_t)ITERS * TOT + i] = sp2 * soft_i + Sb[ITERS % 3][i];
}

extern "C" void kernel_launch(void* const* d_in, const int* in_sizes, int n_in,
                              void* d_out, int out_size, void* d_ws, size_t ws_size,
                              hipStream_t stream) {
    const float* soft     = (const float*)d_in[0];
    // d_in[1] labels (int64) unused; d_in[2] dense H unused
    const int*   row_cols = (const int*)d_in[3];
    const float* W1       = (const float*)d_in[4];
    const float* W2       = (const float*)d_in[5];
    const float* bw1      = (const float*)d_in[6];
    const float* bw2      = (const float*)d_in[7];
    float* out = (float*)d_out;

    float* S0 = (float*)d_ws;   // 3 x B*N f32 = 768 KB total
    float* S1 = S0 + TOT;
    float* S2 = S1 + TOT;

    void* args[] = {(void*)&soft, (void*)&row_cols, (void*)&W1, (void*)&W2,
                    (void*)&bw1, (void*)&bw2, (void*)&out,
                    (void*)&S0, (void*)&S1, (void*)&S2};
    hipLaunchCooperativeKernel((void*)k_fused, dim3(BLKS), dim3(THR),
                               args, 0, stream);
}

// Round 4
// 91.923 us; speedup vs baseline: 2.8973x; 2.8973x over previous
//
#include <hip/hip_runtime.h>

// NMS-r BP decoder. Key structure: the computation is fully independent per
// batch element b (cv/temp/S/out all carry leading b). One block per batch:
//   - temp[1024] and colsum S[1024] live in LDS (8 KB/block)
//   - cv (512 checks x 6) lives in registers of the owning thread
//   - column sums via LDS atomicAdd (ds_add_f32), NOT device atomics
//   - iteration sync = __syncthreads(), no grid.sync, no cooperative launch
// Round-2 lesson: 983K device-scope atomics = 26 MB of L2-bypass EA traffic
// + grid syncs at 1 wave/SIMD occupancy -> 180 us of idle latency.

constexpr int BB    = 64;
constexpr int NCOL  = 1024;
constexpr int MROW  = 512;
constexpr int KDC   = 6;
constexpr int ITERS = 5;
constexpr int THR   = 512;            // 1 check/thread, 2 marg items/thread

__device__ __forceinline__ float softplusf(float x) {
    return fmaxf(x, 0.f) + log1pf(expf(-fabsf(x)));
}
__device__ __forceinline__ float sgnf(float x) {
    return (x > 0.f) ? 1.f : ((x < 0.f) ? -1.f : 0.f);
}

__global__ void __launch_bounds__(THR) k_decode(
        const float* __restrict__ soft,      // [B,N]
        const int*   __restrict__ row_cols,  // [M,DC]
        const float* __restrict__ W1,        // [DC-1,4]
        const float* __restrict__ W2,        // [4]
        const float* __restrict__ bw1,
        const float* __restrict__ bw2,
        float* __restrict__ out) {           // [ITERS+1,B,N]
    __shared__ float T[NCOL];   // temp = colsum + sp1*soft
    __shared__ float S[NCOL];   // colsum accumulator for this phase

    const int b   = blockIdx.x;
    const int tid = threadIdx.x;
    const int m   = tid;                       // my check row (one per thread)
    const int n0  = tid;                       // my two marg columns
    const int n1  = tid + THR;

    const float sp1 = softplusf(bw1[0]);
    const float sp2 = softplusf(bw2[0]);

    // collapsed NN: w = W1 @ W2 (5-vector); redundant per-thread, L1-hot
    float w[KDC - 1];
#pragma unroll
    for (int j = 0; j < KDC - 1; ++j) {
        float a = 0.f;
#pragma unroll
        for (int q = 0; q < 4; ++q) a += W1[j * 4 + q] * W2[q];
        w[j] = a;
    }

    const float* sb = soft + b * NCOL;
    const float s0 = sb[n0], s1 = sb[n1];
    // out[0] = soft_input; init temp and colsum accumulator
    out[b * NCOL + n0] = s0;
    out[b * NCOL + n1] = s1;
    T[n0] = sp1 * s0;  T[n1] = sp1 * s1;
    S[n0] = 0.f;       S[n1] = 0.f;

    int   cols[KDC];
    float cv[KDC];
#pragma unroll
    for (int k = 0; k < KDC; ++k) {
        cols[k] = row_cols[m * KDC + k];
        cv[k]   = 0.f;
    }
    __syncthreads();

#pragma unroll
    for (int p = 0; p < ITERS; ++p) {
        // ---- check-node update (1 check per thread) ----
        float sg[KDC], mag[KDC], P = 1.f;
#pragma unroll
        for (int k = 0; k < KDC; ++k) {
            float v = T[cols[k]] - cv[k];      // vc at my nonzeros
            float s = sgnf(v);
            sg[k] = s;  P *= s;
            mag[k] = fabsf(v);
        }
        // stable ranks: a permutation even under ties (tie order value-safe)
        int rank[KDC];
#pragma unroll
        for (int k = 0; k < KDC; ++k) {
            int r = 0;
#pragma unroll
            for (int j = 0; j < KDC; ++j)
                r += (mag[j] < mag[k]) || (mag[j] == mag[k] && j < k);
            rank[k] = r;
        }
        // sorted mags via static predicated selects (no scratch, rule #20)
        float srt[KDC];
#pragma unroll
        for (int r = 0; r < KDC; ++r) {
            float v = 0.f;
#pragma unroll
            for (int k = 0; k < KDC; ++k) v = (rank[k] == r) ? mag[k] : v;
            srt[r] = v;
        }
        // leave-one-out dot with w via prefix/suffix over sorted-6
        float pre[KDC];
        pre[0] = 0.f;
#pragma unroll
        for (int r = 0; r < KDC - 1; ++r) pre[r + 1] = pre[r] + srt[r] * w[r];
        float suf[KDC];
        suf[KDC - 1] = 0.f;
#pragma unroll
        for (int r = KDC - 2; r >= 0; --r) suf[r] = suf[r + 1] + srt[r + 1] * w[r];
        float valr[KDC];
#pragma unroll
        for (int r = 0; r < KDC; ++r) valr[r] = pre[r] + suf[r];

#pragma unroll
        for (int k = 0; k < KDC; ++k) {
            float val = 0.f;
#pragma unroll
            for (int r = 0; r < KDC; ++r) val = (rank[k] == r) ? valr[r] : val;
            float cvn = P * sg[k] * val;
            cv[k] = cvn;
            atomicAdd(&S[cols[k]], cvn);       // LDS ds_add_f32, block-local
        }
        __syncthreads();

        // ---- marginalize + next temp (2 columns per thread) ----
        float a0 = S[n0], a1 = S[n1];
        float* op = out + (size_t)(p + 1) * (BB * NCOL) + b * NCOL;
        op[n0] = fmaf(sp2, s0, a0);
        op[n1] = fmaf(sp2, s1, a1);
        T[n0] = fmaf(sp1, s0, a0);
        T[n1] = fmaf(sp1, s1, a1);
        S[n0] = 0.f;  S[n1] = 0.f;             // ready for next phase
        __syncthreads();
    }
}

extern "C" void kernel_launch(void* const* d_in, const int* in_sizes, int n_in,
                              void* d_out, int out_size, void* d_ws, size_t ws_size,
                              hipStream_t stream) {
    const float* soft     = (const float*)d_in[0];
    // d_in[1] labels (int64) unused; d_in[2] dense H unused
    const int*   row_cols = (const int*)d_in[3];
    const float* W1       = (const float*)d_in[4];
    const float* W2       = (const float*)d_in[5];
    const float* bw1      = (const float*)d_in[6];
    const float* bw2      = (const float*)d_in[7];
    float* out = (float*)d_out;

    k_decode<<<dim3(BB), dim3(THR), 0, stream>>>(soft, row_cols, W1, W2,
                                                 bw1, bw2, out);
}

// Round 6
// 90.439 us; speedup vs baseline: 2.9448x; 1.0164x over previous
//
#include <hip/hip_runtime.h>

// NMS-r BP decoder, one block per batch element (b-independent computation).
// Round-4 lesson: kernel is STALL-bound (VALUBusy 2.3%, 43us) — per-iteration
// critical path (LDS gather latency + deep sort chain + 2 barriers) with only
// 2 waves/SIMD. This round:
//  - 3 rotating LDS colsum buffers S[3][N]: read / atomic-acc / zero all in
//    one phase -> ONE __syncthreads per iteration (6 total, was 10). temp is
//    never materialized: check reads S[c]+SPS[c]-cv (same association as ref).
//  - sort via 15-CE insertion network on (v,col) pairs, compare on fabs
//    (abs modifier is free) -> ~75 VALU vs ~350 for rank+select scatter.
//    cv/cols stay permuted across iterations: edges are an unordered set;
//    ties are value-safe (equal mags -> equal leave-one-out dots).
//  - gathers issued first so marg/zero/global-store work hides their latency.

constexpr int BB    = 64;
constexpr int NCOL  = 1024;
constexpr int KDC   = 6;
constexpr int ITERS = 5;
constexpr int THR   = 512;            // 1 check/thread, 2 marg cols/thread
constexpr int TOT   = BB * NCOL;

__device__ __forceinline__ float softplusf(float x) {
    return fmaxf(x, 0.f) + log1pf(expf(-fabsf(x)));
}
__device__ __forceinline__ float sgnf(float x) {
    return (x > 0.f) ? 1.f : ((x < 0.f) ? -1.f : 0.f);
}

__global__ void __launch_bounds__(THR) k_decode(
        const float* __restrict__ soft,      // [B,N]
        const int*   __restrict__ row_cols,  // [M,DC]
        const float* __restrict__ W1,        // [DC-1,4]
        const float* __restrict__ W2,        // [4]
        const float* __restrict__ bw1,
        const float* __restrict__ bw2,
        float* __restrict__ out) {           // [ITERS+1,B,N]
    __shared__ float SPS[NCOL];      // sp1 * soft (iteration-invariant)
    __shared__ float S[3][NCOL];     // rotating colsum buffers

    const int tid = threadIdx.x;
    const int b   = blockIdx.x;
    const int n0  = tid, n1 = tid + THR;

    const float sp1 = softplusf(bw1[0]);
    const float sp2 = softplusf(bw2[0]);

    // collapsed NN: w = W1 @ W2 (5-vector), redundant per-thread (L1-hot)
    float w[KDC - 1];
#pragma unroll
    for (int j = 0; j < KDC - 1; ++j) {
        float a = 0.f;
#pragma unroll
        for (int q = 0; q < 4; ++q) a += W1[j * 4 + q] * W2[q];
        w[j] = a;
    }

    const float* sb = soft + b * NCOL;
    const float s0 = sb[n0], s1 = sb[n1];
    out[b * NCOL + n0] = s0;                 // soft_output_list[0]
    out[b * NCOL + n1] = s1;
    SPS[n0] = sp1 * s0;  SPS[n1] = sp1 * s1;
    S[1][n0] = 0.f;      S[1][n1] = 0.f;     // acc buffer for phase 0

    int   cols[KDC];                         // permuted alongside cv by sort
    float cv[KDC];
#pragma unroll
    for (int k = 0; k < KDC; ++k) {
        cols[k] = row_cols[tid * KDC + k];
        cv[k]   = 0.f;
    }
    __syncthreads();

    // phase p: read S[p%3] (prev colsum), atomics into S[(p+1)%3] (pre-zeroed),
    // zero S[(p+2)%3] (idle this phase). First acc use of S[0] is p=2; it is
    // zeroed at p=1. S[0] is never read at p=0 (special case).
#pragma unroll
    for (int p = 0; p < ITERS; ++p) {
        const int rd = p % 3, ac = (p + 1) % 3, zr = (p + 2) % 3;

        // ---- gathers first (latency) + vc ----
        float v[KDC];
#pragma unroll
        for (int k = 0; k < KDC; ++k) {
            const int c = cols[k];
            v[k] = (p == 0) ? SPS[c] : (S[rd][c] + SPS[c] - cv[k]);
        }

        // ---- marginalize iteration p (reads same S[rd]) ----
        if (p >= 1) {
            const float a0 = S[rd][n0], a1 = S[rd][n1];
            float* op = out + (size_t)p * TOT + b * NCOL;
            op[n0] = fmaf(sp2, s0, a0);
            op[n1] = fmaf(sp2, s1, a1);
        }
        S[zr][n0] = 0.f;  S[zr][n1] = 0.f;   // prep next phase's acc

        // ---- sort (v,cols) ascending by |v|: insertion network, 15 CE ----
#define CE(i, j) { bool sw = fabsf(v[i]) > fabsf(v[j]);                  \
        float tv = sw ? v[j] : v[i]; v[j] = sw ? v[i] : v[j]; v[i] = tv; \
        int tc = sw ? cols[j] : cols[i];                                  \
        cols[j] = sw ? cols[i] : cols[j]; cols[i] = tc; }
        CE(0,1)
        CE(1,2) CE(0,1)
        CE(2,3) CE(1,2) CE(0,1)
        CE(3,4) CE(2,3) CE(1,2) CE(0,1)
        CE(4,5) CE(3,4) CE(2,3) CE(1,2) CE(0,1)
#undef CE

        float mr[KDC], sg[KDC];
#pragma unroll
        for (int r = 0; r < KDC; ++r) { sg[r] = sgnf(v[r]); mr[r] = fabsf(v[r]); }
        const float P = sg[0] * sg[1] * sg[2] * sg[3] * sg[4] * sg[5];

        // leave-one-out dot via prefix/suffix over the sorted 6
        float pre[KDC];
        pre[0] = 0.f;
#pragma unroll
        for (int r = 0; r < KDC - 1; ++r) pre[r + 1] = pre[r] + mr[r] * w[r];
        float suf[KDC];
        suf[KDC - 1] = 0.f;
#pragma unroll
        for (int r = KDC - 2; r >= 0; --r) suf[r] = suf[r + 1] + mr[r + 1] * w[r];

#pragma unroll
        for (int r = 0; r < KDC; ++r) {
            const float cvn = P * sg[r] * (pre[r] + suf[r]);
            cv[r] = cvn;                       // stays aligned with cols[r]
            atomicAdd(&S[ac][cols[r]], cvn);   // block-local ds_add_f32
        }
        __syncthreads();
    }

    // final marginalize: phase ITERS-1 accumulated into S[ITERS%3]
    float* op = out + (size_t)ITERS * TOT + b * NCOL;
    op[n0] = fmaf(sp2, s0, S[ITERS % 3][n0]);
    op[n1] = fmaf(sp2, s1, S[ITERS % 3][n1]);
}

extern "C" void kernel_launch(void* const* d_in, const int* in_sizes, int n_in,
                              void* d_out, int out_size, void* d_ws, size_t ws_size,
                              hipStream_t stream) {
    const float* soft     = (const float*)d_in[0];
    // d_in[1] labels (int64) unused; d_in[2] dense H unused
    const int*   row_cols = (const int*)d_in[3];
    const float* W1       = (const float*)d_in[4];
    const float* W2       = (const float*)d_in[5];
    const float* bw1      = (const float*)d_in[6];
    const float* bw2      = (const float*)d_in[7];
    float* out = (float*)d_out;

    k_decode<<<dim3(BB), dim3(THR), 0, stream>>>(soft, row_cols, W1, W2,
                                                 bw1, bw2, out);
}